// Round 7
// baseline (395.871 us; speedup 1.0000x reference)
//
#include <hip/hip_runtime.h>
#include <cstdint>

#define NH 16
#define DH 64
#define FF 4096
#define PP 512
#define BB 2048

typedef __bf16 bf16x8 __attribute__((ext_vector_type(8)));
typedef float f32x4 __attribute__((ext_vector_type(4)));
typedef float f32x16 __attribute__((ext_vector_type(16)));
typedef float fl4 __attribute__((ext_vector_type(4)));
typedef unsigned short us4 __attribute__((ext_vector_type(4)));
typedef unsigned int u32x2 __attribute__((ext_vector_type(2)));

__device__ __forceinline__ unsigned short f2bf(float f) {
  unsigned u = __float_as_uint(f);
  u += 0x7FFFu + ((u >> 16) & 1u);
  return (unsigned short)(u >> 16);
}

// pack two f32 -> two bf16 (round-half-up: +0x8000, take high16s via v_perm)
__device__ __forceinline__ unsigned int pkbf(float lo, float hi) {
  unsigned a = __float_as_uint(lo) + 0x8000u;
  unsigned b = __float_as_uint(hi) + 0x8000u;
  return __builtin_amdgcn_perm(b, a, 0x07060302u);
}

// async global->LDS, 16B/lane. LDS dest = wave-uniform base + lane*16;
// global source is per-lane arbitrary (exploited for the XOR swizzle).
__device__ __forceinline__ void gload_lds16(const void* g, void* l) {
  __builtin_amdgcn_global_load_lds(
      (const __attribute__((address_space(1))) void*)g,
      (__attribute__((address_space(3))) void*)(unsigned int)(unsigned long long)l,
      16, 0, 0);
}

// convert features + prototypes fp32 -> bf16 (x is consumed fp32 directly)
__global__ void cvt_fp(const float* __restrict__ f, const float* __restrict__ p,
                       unsigned short* __restrict__ fb,
                       unsigned short* __restrict__ pb) {
  const int nf = FF * 1024 / 4, np = PP * 1024 / 4;
  int i = blockIdx.x * blockDim.x + threadIdx.x;
  const fl4* src;
  us4* dst;
  if (i < nf) {
    src = (const fl4*)f + i;
    dst = (us4*)fb + i;
  } else if (i < nf + np) {
    src = (const fl4*)p + (i - nf);
    dst = (us4*)pb + (i - nf);
  } else {
    return;
  }
  fl4 v = *src;
  us4 o;
  o.x = f2bf(v.x); o.y = f2bf(v.y); o.z = f2bf(v.z); o.w = f2bf(v.w);
  *dst = o;
}

// ---------------------------------------------------------------------------
// Phase 1: per-head [P x F, K=64] GEMM on prototypes.
//   Q1 = th*Pw + al*Pp - al,  Q2 = be*Pw   (layout [h][p][f], bf16)
//   pws[h][p] += be * sum_f Pw
// ---------------------------------------------------------------------------
__global__ __launch_bounds__(256, 2) void gemm_proto(
    const unsigned short* __restrict__ Abf, const unsigned short* __restrict__ Fbf,
    unsigned short* __restrict__ O1, unsigned short* __restrict__ O2,
    float* __restrict__ pws,
    const float* __restrict__ theta, const float* __restrict__ alpha,
    const float* __restrict__ beta) {
  const int h = blockIdx.z;
  const int n0 = blockIdx.x * 128;   // f tile
  const int lm0 = blockIdx.y * 128;  // p tile
  const int t = threadIdx.x;

  __shared__ __align__(16) char As[128 * 128];
  __shared__ __align__(16) char Bs[128 * 128];

  {
    const char* ab = (const char*)(Abf + (size_t)lm0 * 1024 + h * 64);
    const char* bb = (const char*)(Fbf + (size_t)n0 * 1024 + h * 64);
#pragma unroll
    for (int r = 0; r < 4; ++r) {
      int o = r * 4096 + t * 16;
      int row = o >> 7, col = o & 127;
      gload_lds16(ab + (size_t)row * 2048 + col, As + o);
      gload_lds16(bb + (size_t)row * 2048 + col, Bs + o);
    }
  }
  __syncthreads();

  const int wave = t >> 6, lane = t & 63;
  const int wm = wave & 1, wn = wave >> 1;
  const int quad = lane >> 4, lr = lane & 15;

  f32x4 acc[4][4];
#pragma unroll
  for (int i = 0; i < 4; ++i)
#pragma unroll
    for (int j = 0; j < 4; ++j) acc[i][j] = (f32x4){0.f, 0.f, 0.f, 0.f};

#pragma unroll
  for (int s = 0; s < 2; ++s) {
    bf16x8 av[4], bv[4];
#pragma unroll
    for (int fm = 0; fm < 4; ++fm) {
      int row = wm * 64 + fm * 16 + lr;
      av[fm] = *(const bf16x8*)(As + row * 128 + s * 64 + quad * 16);
    }
#pragma unroll
    for (int fn = 0; fn < 4; ++fn) {
      int row = wn * 64 + fn * 16 + lr;
      bv[fn] = *(const bf16x8*)(Bs + row * 128 + s * 64 + quad * 16);
    }
#pragma unroll
    for (int fm = 0; fm < 4; ++fm)
#pragma unroll
      for (int fn = 0; fn < 4; ++fn)
        acc[fm][fn] = __builtin_amdgcn_mfma_f32_16x16x32_bf16(av[fm], bv[fn],
                                                              acc[fm][fn], 0, 0, 0);
  }

  const float th = theta[h], al = alpha[h], be = beta[h];

#pragma unroll
  for (int fm = 0; fm < 4; ++fm) {
    int prow = lm0 + wm * 64 + fm * 16 + quad * 4;
    float rs0 = 0.f, rs1 = 0.f, rs2 = 0.f, rs3 = 0.f;
#pragma unroll
    for (int fn = 0; fn < 4; ++fn) {
      int f = n0 + wn * 64 + fn * 16 + lr;
#pragma unroll
      for (int i = 0; i < 4; ++i) {
        float pf = acc[fm][fn][i];
        float pp = fmaxf(pf, 0.f);
        float pw = pf * pp;
        size_t idx = ((size_t)(h * PP + prow + i)) * FF + f;
        O1[idx] = f2bf(th * pw + al * pp - al);
        O2[idx] = f2bf(be * pw);
        if (i == 0) rs0 += pw;
        else if (i == 1) rs1 += pw;
        else if (i == 2) rs2 += pw;
        else rs3 += pw;
      }
    }
    float rs[4] = {rs0, rs1, rs2, rs3};
#pragma unroll
    for (int i = 0; i < 4; ++i) {
      float s = rs[i];
      s += __shfl_xor(s, 1);
      s += __shfl_xor(s, 2);
      s += __shfl_xor(s, 4);
      s += __shfl_xor(s, 8);
      if (lr == 0) atomicAdd(&pws[h * PP + prow + i], be * s);
    }
  }
}

// ---------------------------------------------------------------------------
// Fused main, round-12: 32x32x16 D-step + counted-vmcnt Q rotation.
//   Rounds 2/3/4/6: MfmaUtil pinned at ~46% across three schedule variants
//   -> limiter is per-MFMA economics, not schedule. Changes:
//   (1) D uses v_mfma_f32_32x32x16_bf16: 32 MFMAs/wave/iter instead of 64;
//       17% less matrix-pipe time per FLOP (2382 vs 2075 TF measured), half
//       the issue slots, 32-cyc-deep ops bridge short stalls.
//       acc = [4 b-tiles][2 p-tiles] f32x16 = 128 regs (same budget).
//       A-frag (X): lane(m = l&31 -> b-row, k = (l>>5)*8+j -> f).
//       B-frag (Q): lane(n = l&31 -> p,     k = (l>>5)*8+j -> f).
//       C/D: col(p) = l&31, row(b) = (reg&3)+8*(reg>>2)+4*(l>>5)  [m74/m101].
//   (2) T4 counted vmcnt: Q(it+1) loads issue at body END into the same
//       (dead) q regs and stay in flight across the barrier; body-end wait
//       is vmcnt(8) (drains only the older sF DMA), never 0. Q-consume
//       cover ~350 -> ~800+ cyc. Zero extra VGPRs (rotation).
//   Loop unrolled x2 so all LDS buffer selects are compile-time immediates.
//   Retains: B-step 16x16x32, CPACK, sX XOR-swizzle layout, XCD-aware
//   decode (T1), B/C one iteration ahead, fenced C/D interleave, fused
//   waitcnt+s_barrier single asm (round-7 race fix), setprio.
// LDS = 8 (sF x2) + 16 (sXw x2) + 16 (sXp x2) = 40 KB; 2 blocks/CU.
// ---------------------------------------------------------------------------
__global__ __launch_bounds__(256, 2) void fused_main(
    const float* __restrict__ x, const unsigned short* __restrict__ f_bf,
    const unsigned short* __restrict__ Q1, const unsigned short* __restrict__ Q2,
    const float* __restrict__ pws, float* __restrict__ out) {
  // XCD-aware decode: l -> (p-tile, head, b-tile) with Q-sharers co-located.
  const int l = blockIdx.x;        // 0..511
  const int i = l >> 3;            // 0..63 within XCD
  const int g = (l & 7) * 4 + (i & 3);  // group = (p-tile, head), 0..31
  const int h = g >> 1;
  const int n0 = (g & 1) * 256;    // p tile
  const int m0 = (i >> 2) * 128;   // b tile
  const int t = threadIdx.x;
  const int wave = t >> 6, lane = t & 63;
  const int quad = lane >> 4, lr = lane & 15;
  const int el = lane & 31, half = lane >> 5;   // 32x32 fragment coords
  const int key8 = lr & 7;         // swizzle key for 128B-row buffer (sF)
  const int key2 = (lr >> 1) & 3;  // swizzle key for 64B-row buffers (sX*)

  __shared__ __align__(16) char sF[2 * 4096];
  __shared__ __align__(16) char sXw[2 * 8192];
  __shared__ __align__(16) char sXp[2 * 8192];

  // Xh B-operand fragments (16x16x32 B-step), loaded fp32, packed in-reg.
  bf16x8 xh[2][2];
#pragma unroll
  for (int bn = 0; bn < 2; ++bn)
#pragma unroll
    for (int s = 0; s < 2; ++s) {
      int b = m0 + wave * 32 + bn * 16 + lr;
      const float* xr = x + (size_t)b * 1024 + h * 64 + s * 32 + quad * 8;
      fl4 v0 = *(const fl4*)xr;
      fl4 v1 = *(const fl4*)(xr + 4);
      union { unsigned u[4]; bf16x8 v; } cv;
      cv.u[0] = pkbf(v0.x, v0.y);
      cv.u[1] = pkbf(v0.z, v0.w);
      cv.u[2] = pkbf(v1.x, v1.y);
      cv.u[3] = pkbf(v1.z, v1.w);
      xh[bn][s] = cv.v;
    }

  // ---- hoisted (loop-invariant) LDS byte offsets ----
  int af_off[2][2];  // B reads: sF row fm*16+lr, global chunk s*4+quad
#pragma unroll
  for (int fm = 0; fm < 2; ++fm)
#pragma unroll
    for (int s = 0; s < 2; ++s)
      af_off[fm][s] = (fm * 16 + lr) * 128 + (((s * 4 + quad) ^ key8) * 16);

  int cw_off[2][2];  // C writes: row wave*32+bn*16+lr, chunk fm*2+(quad>>1)
#pragma unroll
  for (int fm = 0; fm < 2; ++fm)
#pragma unroll
    for (int bn = 0; bn < 2; ++bn)
      cw_off[fm][bn] = (wave * 32 + bn * 16 + lr) * 64 +
                       (((fm * 2 + (quad >> 1)) ^ key2) * 16) + (quad & 1) * 8;

  // D A-frag reads (32x32x16): row = mt*32 + el, logical 16B chunk =
  // ks*2 + half, physical = logical ^ ((el&15)>>1 & 3) [matches cw swizzle;
  // (row>>1)&3 == ((row mod 16)>>1)&3 since row steps are multiples of 16].
  int axk[2];
  {
    int keyel = ((el & 15) >> 1) & 3;
#pragma unroll
    for (int ks = 0; ks < 2; ++ks)
      axk[ks] = el * 64 + (((ks * 2 + half) ^ keyel) * 16);
  }

  // sF staging source (swizzle applied on the GLOBAL side)
  const char* srcF;
  {
    int row = t >> 3, c = t & 7, cs = c ^ (row & 7);
    srcF = (const char*)f_bf + h * 128 + (size_t)row * 2048 + cs * 16;
  }

  // Q addressing: block-uniform base (SGPR) + per-lane 32-bit byte offset.
  // Lane layout (32x32 B-frag): p = wave*64 + nt*32 + el, f = ks*16+half*8+j.
  const char* qb1 = (const char*)Q1 + (size_t)(h * PP + n0) * FF * 2;
  const char* qb2 = (const char*)Q2 + (size_t)(h * PP + n0) * FF * 2;
  unsigned qo = (unsigned)(((wave * 64 + el) * FF + half * 8) * 2);

  f32x16 acc[4][2];
#pragma unroll
  for (int mt = 0; mt < 4; ++mt)
#pragma unroll
    for (int nt = 0; nt < 2; ++nt)
#pragma unroll
      for (int r = 0; r < 16; ++r) acc[mt][nt][r] = 0.f;

  f32x4 xf[2][2];
  bf16x8 q1v[2][2], q2v[2][2];  // [nt][ks], rotated across iterations
  bf16x8 awf[2][2], apf[2][2];  // [m-local][ks]

// B(k): Xf from sF buf SFB into xf (8 x 16x16x32 MFMA)
#define BSTEP(SFB) do {                                                      \
    _Pragma("unroll") for (int fm_ = 0; fm_ < 2; ++fm_)                      \
      _Pragma("unroll") for (int bn_ = 0; bn_ < 2; ++bn_)                    \
        xf[fm_][bn_] = (f32x4){0.f, 0.f, 0.f, 0.f};                          \
    _Pragma("unroll") for (int s_ = 0; s_ < 2; ++s_)                         \
      _Pragma("unroll") for (int fm_ = 0; fm_ < 2; ++fm_) {                  \
        bf16x8 af_ = *(const bf16x8*)(sF + (SFB) + af_off[fm_][s_]);         \
        _Pragma("unroll") for (int bn_ = 0; bn_ < 2; ++bn_)                  \
          xf[fm_][bn_] = __builtin_amdgcn_mfma_f32_16x16x32_bf16(            \
              af_, xh[bn_][s_], xf[fm_][bn_], 0, 0, 0);                      \
      }                                                                      \
  } while (0)

// C pack group (FM,BN) -> sXw/sXp at byte base XB (~20 VALU + 2 ds_write)
#define CPACK(FM, BN, XB) do {                                               \
    float v0_ = xf[FM][BN][0], v1_ = xf[FM][BN][1];                          \
    float v2_ = xf[FM][BN][2], v3_ = xf[FM][BN][3];                          \
    float p0_ = fmaxf(v0_, 0.f), p1_ = fmaxf(v1_, 0.f);                      \
    float p2_ = fmaxf(v2_, 0.f), p3_ = fmaxf(v3_, 0.f);                      \
    u32x2 w_, p_;                                                            \
    w_.x = pkbf(v0_ * p0_, v1_ * p1_);                                       \
    w_.y = pkbf(v2_ * p2_, v3_ * p3_);                                       \
    p_.x = pkbf(p0_, p1_);                                                   \
    p_.y = pkbf(p2_, p3_);                                                   \
    *(u32x2*)(sXw + (XB) + cw_off[FM][BN]) = w_;                             \
    *(u32x2*)(sXp + (XB) + cw_off[FM][BN]) = p_;                             \
  } while (0)

// D operand reads for mt-pair P from sX buf XA (8 ds_read_b128)
#define DREAD32(P, XA) do {                                                  \
    _Pragma("unroll") for (int m_ = 0; m_ < 2; ++m_)                         \
      _Pragma("unroll") for (int ks_ = 0; ks_ < 2; ++ks_) {                  \
        awf[m_][ks_] =                                                       \
            *(const bf16x8*)(sXw + (XA) + (P) * 4096 + m_ * 2048 + axk[ks_]);\
        apf[m_][ks_] =                                                       \
            *(const bf16x8*)(sXp + (XA) + (P) * 4096 + m_ * 2048 + axk[ks_]);\
      }                                                                      \
  } while (0)

// D MFMA quarter: mt-pair P, k-step KS (8 x 32x32x16 MFMA)
#define DM32(P, KS) do {                                                     \
    _Pragma("unroll") for (int m_ = 0; m_ < 2; ++m_)                         \
      _Pragma("unroll") for (int nt_ = 0; nt_ < 2; ++nt_) {                  \
        acc[(P) * 2 + m_][nt_] = __builtin_amdgcn_mfma_f32_32x32x16_bf16(    \
            awf[m_][KS], q1v[nt_][KS], acc[(P) * 2 + m_][nt_], 0, 0, 0);     \
        acc[(P) * 2 + m_][nt_] = __builtin_amdgcn_mfma_f32_32x32x16_bf16(    \
            apf[m_][KS], q2v[nt_][KS], acc[(P) * 2 + m_][nt_], 0, 0, 0);     \
      }                                                                      \
  } while (0)

// Q fragment loads (8 x 16B global, L2-hit); rotated: loaded one iter ahead
#define QLOAD() do {                                                         \
    _Pragma("unroll") for (int nt_ = 0; nt_ < 2; ++nt_)                      \
      _Pragma("unroll") for (int ks_ = 0; ks_ < 2; ++ks_) {                  \
        q1v[nt_][ks_] =                                                      \
            *(const bf16x8*)(qb1 + qo + nt_ * 262144 + ks_ * 32);            \
        q2v[nt_][ks_] =                                                      \
            *(const bf16x8*)(qb2 + qo + nt_ * 262144 + ks_ * 32);            \
      }                                                                      \
  } while (0)

// One pipeline body. PA: D reads sX[PA], stage writes sF[PA].
// PB = PA^1: B reads sF[PB], C writes sX[PB]. All compile-time.
#define BODY(PA_, PB_) do {                                                  \
    gload_lds16(srcF, sF + (PA_) * 4096 + t * 16);                           \
    srcF += 32 * 2048;                                                       \
    BSTEP((PB_) * 4096);                                                     \
    DREAD32(0, (PA_) * 8192);                                                \
    __builtin_amdgcn_sched_barrier(0);                                       \
    __builtin_amdgcn_s_setprio(1);                                           \
    CPACK(0, 0, (PB_) * 8192);                                               \
    DM32(0, 0);                                                              \
    __builtin_amdgcn_sched_barrier(0);                                       \
    CPACK(0, 1, (PB_) * 8192);                                               \
    DM32(0, 1);                                                              \
    DREAD32(1, (PA_) * 8192);                                                \
    __builtin_amdgcn_sched_barrier(0);                                       \
    CPACK(1, 0, (PB_) * 8192);                                               \
    DM32(1, 0);                                                              \
    __builtin_amdgcn_sched_barrier(0);                                       \
    CPACK(1, 1, (PB_) * 8192);                                               \
    DM32(1, 1);                                                              \
    __builtin_amdgcn_s_setprio(0);                                           \
    QLOAD();                                                                 \
    qo += 64;                                                                \
    /* counted wait: keep the 8 fresh Q loads in flight across the       */  \
    /* barrier; drain only older vmem (the sF DMA). lgkmcnt(0) publishes */  \
    /* C ds_writes and closes D ds_reads. Single asm: no scheduler gap.  */  \
    asm volatile("s_waitcnt vmcnt(8) lgkmcnt(0)\n\ts_barrier" ::: "memory"); \
    __builtin_amdgcn_sched_barrier(0);                                       \
  } while (0)

  // ---- prologue ----
  gload_lds16(srcF, sF + t * 16);          // tile0 -> sF buf0
  srcF += 32 * 2048;
  asm volatile("s_waitcnt vmcnt(0)\n\ts_barrier" ::: "memory");
  __builtin_amdgcn_sched_barrier(0);
  gload_lds16(srcF, sF + 4096 + t * 16);   // tile1 -> sF buf1
  srcF += 32 * 2048;
  BSTEP(0);                                 // B(0)+C(0) -> sXw/sXp buf0
  CPACK(0, 0, 0);
  CPACK(0, 1, 0);
  CPACK(1, 0, 0);
  CPACK(1, 1, 0);
  QLOAD();                                  // Q(0)
  qo += 64;
  asm volatile("s_waitcnt vmcnt(8) lgkmcnt(0)\n\ts_barrier" ::: "memory");
  __builtin_amdgcn_sched_barrier(0);

  for (int it2 = 0; it2 < FF / 64; ++it2) {
    BODY(0, 1);
    BODY(1, 0);
  }

  // epilogue: subtract pws, store fp32 (32x32 C/D layout)
#pragma unroll
  for (int nt = 0; nt < 2; ++nt) {
    int p = n0 + wave * 64 + nt * 32 + el;
    float sub = pws[h * PP + p];
#pragma unroll
    for (int mt = 0; mt < 4; ++mt) {
#pragma unroll
      for (int gi = 0; gi < 4; ++gi) {
#pragma unroll
        for (int r = 0; r < 4; ++r) {
          int b = m0 + mt * 32 + gi * 8 + half * 4 + r;
          out[(size_t)b * (NH * PP) + h * PP + p] = acc[mt][nt][gi * 4 + r] - sub;
        }
      }
    }
  }
}

extern "C" void kernel_launch(void* const* d_in, const int* in_sizes, int n_in,
                              void* d_out, int out_size, void* d_ws, size_t ws_size,
                              hipStream_t stream) {
  const float* x = (const float*)d_in[0];
  const float* features = (const float*)d_in[1];
  const float* prototypes = (const float*)d_in[2];
  const float* theta = (const float*)d_in[3];
  const float* alpha = (const float*)d_in[4];
  const float* beta = (const float*)d_in[5];
  float* out = (float*)d_out;

  char* ws = (char*)d_ws;
  size_t off = 0;
  auto carve = [&](size_t bytes) -> char* {
    char* p = ws + off;
    off += (bytes + 255) & ~(size_t)255;
    return p;
  };
  // f_bf padded by 64 rows: fused_main's pipelined loop prefetches up to two
  // tiles past the end (data unused; keeps the main loop branch-free).
  unsigned short* f_bf = (unsigned short*)carve((size_t)(FF + 64) * 1024 * 2);
  unsigned short* p_bf = (unsigned short*)carve((size_t)PP * 1024 * 2);
  unsigned short* Q1 = (unsigned short*)carve((size_t)NH * PP * FF * 2);
  unsigned short* Q2 = (unsigned short*)carve((size_t)NH * PP * FF * 2);
  float* pws = (float*)carve((size_t)NH * PP * 4);

  const int ncvt = (FF + PP) * 1024 / 4;
  cvt_fp<<<(ncvt + 255) / 256, 256, 0, stream>>>(features, prototypes, f_bf, p_bf);
  hipMemsetAsync(pws, 0, (size_t)NH * PP * 4, stream);

  // Phase 1: prototypes -> Q1, Q2, pws
  gemm_proto<<<dim3(FF / 128, PP / 128, NH), 256, 0, stream>>>(
      p_bf, f_bf, Q1, Q2, pws, theta, alpha, beta);

  // Fused main GEMM (1-D grid, XCD-aware decode in-kernel)
  fused_main<<<dim3(512, 1, 1), 256, 0, stream>>>(
      x, f_bf, Q1, Q2, pws, out);
}

// Round 8
// 393.821 us; speedup vs baseline: 1.0052x; 1.0052x over previous
//
#include <hip/hip_runtime.h>
#include <cstdint>

#define NH 16
#define DH 64
#define FF 4096
#define PP 512
#define BB 2048

typedef __bf16 bf16x8 __attribute__((ext_vector_type(8)));
typedef float f32x4 __attribute__((ext_vector_type(4)));
typedef float f32x16 __attribute__((ext_vector_type(16)));
typedef float fl4 __attribute__((ext_vector_type(4)));
typedef unsigned short us4 __attribute__((ext_vector_type(4)));
typedef unsigned int u32x2 __attribute__((ext_vector_type(2)));

__device__ __forceinline__ unsigned short f2bf(float f) {
  unsigned u = __float_as_uint(f);
  u += 0x7FFFu + ((u >> 16) & 1u);
  return (unsigned short)(u >> 16);
}

// pack two f32 -> two bf16 (round-half-up: +0x8000, take high16s via v_perm)
__device__ __forceinline__ unsigned int pkbf(float lo, float hi) {
  unsigned a = __float_as_uint(lo) + 0x8000u;
  unsigned b = __float_as_uint(hi) + 0x8000u;
  return __builtin_amdgcn_perm(b, a, 0x07060302u);
}

// async global->LDS, 16B/lane. LDS dest = wave-uniform base + lane*16;
// global source is per-lane arbitrary (exploited for the XOR swizzle).
__device__ __forceinline__ void gload_lds16(const void* g, void* l) {
  __builtin_amdgcn_global_load_lds(
      (const __attribute__((address_space(1))) void*)g,
      (__attribute__((address_space(3))) void*)(unsigned int)(unsigned long long)l,
      16, 0, 0);
}

// convert features + prototypes fp32 -> bf16 (x is consumed fp32 directly)
__global__ void cvt_fp(const float* __restrict__ f, const float* __restrict__ p,
                       unsigned short* __restrict__ fb,
                       unsigned short* __restrict__ pb) {
  const int nf = FF * 1024 / 4, np = PP * 1024 / 4;
  int i = blockIdx.x * blockDim.x + threadIdx.x;
  const fl4* src;
  us4* dst;
  if (i < nf) {
    src = (const fl4*)f + i;
    dst = (us4*)fb + i;
  } else if (i < nf + np) {
    src = (const fl4*)p + (i - nf);
    dst = (us4*)pb + (i - nf);
  } else {
    return;
  }
  fl4 v = *src;
  us4 o;
  o.x = f2bf(v.x); o.y = f2bf(v.y); o.z = f2bf(v.z); o.w = f2bf(v.w);
  *dst = o;
}

// ---------------------------------------------------------------------------
// Phase 1: per-head [P x F, K=64] GEMM on prototypes.
//   Q1 = th*Pw + al*Pp - al,  Q2 = be*Pw   (layout [h][p][f], bf16)
//   pws[h][p] += be * sum_f Pw
// ---------------------------------------------------------------------------
__global__ __launch_bounds__(256, 2) void gemm_proto(
    const unsigned short* __restrict__ Abf, const unsigned short* __restrict__ Fbf,
    unsigned short* __restrict__ O1, unsigned short* __restrict__ O2,
    float* __restrict__ pws,
    const float* __restrict__ theta, const float* __restrict__ alpha,
    const float* __restrict__ beta) {
  const int h = blockIdx.z;
  const int n0 = blockIdx.x * 128;   // f tile
  const int lm0 = blockIdx.y * 128;  // p tile
  const int t = threadIdx.x;

  __shared__ __align__(16) char As[128 * 128];
  __shared__ __align__(16) char Bs[128 * 128];

  {
    const char* ab = (const char*)(Abf + (size_t)lm0 * 1024 + h * 64);
    const char* bb = (const char*)(Fbf + (size_t)n0 * 1024 + h * 64);
#pragma unroll
    for (int r = 0; r < 4; ++r) {
      int o = r * 4096 + t * 16;
      int row = o >> 7, col = o & 127;
      gload_lds16(ab + (size_t)row * 2048 + col, As + o);
      gload_lds16(bb + (size_t)row * 2048 + col, Bs + o);
    }
  }
  __syncthreads();

  const int wave = t >> 6, lane = t & 63;
  const int wm = wave & 1, wn = wave >> 1;
  const int quad = lane >> 4, lr = lane & 15;

  f32x4 acc[4][4];
#pragma unroll
  for (int i = 0; i < 4; ++i)
#pragma unroll
    for (int j = 0; j < 4; ++j) acc[i][j] = (f32x4){0.f, 0.f, 0.f, 0.f};

#pragma unroll
  for (int s = 0; s < 2; ++s) {
    bf16x8 av[4], bv[4];
#pragma unroll
    for (int fm = 0; fm < 4; ++fm) {
      int row = wm * 64 + fm * 16 + lr;
      av[fm] = *(const bf16x8*)(As + row * 128 + s * 64 + quad * 16);
    }
#pragma unroll
    for (int fn = 0; fn < 4; ++fn) {
      int row = wn * 64 + fn * 16 + lr;
      bv[fn] = *(const bf16x8*)(Bs + row * 128 + s * 64 + quad * 16);
    }
#pragma unroll
    for (int fm = 0; fm < 4; ++fm)
#pragma unroll
      for (int fn = 0; fn < 4; ++fn)
        acc[fm][fn] = __builtin_amdgcn_mfma_f32_16x16x32_bf16(av[fm], bv[fn],
                                                              acc[fm][fn], 0, 0, 0);
  }

  const float th = theta[h], al = alpha[h], be = beta[h];

#pragma unroll
  for (int fm = 0; fm < 4; ++fm) {
    int prow = lm0 + wm * 64 + fm * 16 + quad * 4;
    float rs0 = 0.f, rs1 = 0.f, rs2 = 0.f, rs3 = 0.f;
#pragma unroll
    for (int fn = 0; fn < 4; ++fn) {
      int f = n0 + wn * 64 + fn * 16 + lr;
#pragma unroll
      for (int i = 0; i < 4; ++i) {
        float pf = acc[fm][fn][i];
        float pp = fmaxf(pf, 0.f);
        float pw = pf * pp;
        size_t idx = ((size_t)(h * PP + prow + i)) * FF + f;
        O1[idx] = f2bf(th * pw + al * pp - al);
        O2[idx] = f2bf(be * pw);
        if (i == 0) rs0 += pw;
        else if (i == 1) rs1 += pw;
        else if (i == 2) rs2 += pw;
        else rs3 += pw;
      }
    }
    float rs[4] = {rs0, rs1, rs2, rs3};
#pragma unroll
    for (int i = 0; i < 4; ++i) {
      float s = rs[i];
      s += __shfl_xor(s, 1);
      s += __shfl_xor(s, 2);
      s += __shfl_xor(s, 4);
      s += __shfl_xor(s, 8);
      if (lr == 0) atomicAdd(&pws[h * PP + prow + i], be * s);
    }
  }
}

// ---------------------------------------------------------------------------
// Fused main, round-13: cross-block anti-phase stagger.
//   Rounds 2-7: five schedule/shape variants all at 297-304us, MfmaUtil
//   46+-1%. Model: matrix pipes are per-SIMD (32x32x16 ~ 32cyc/SIMD); per
//   wave-iter matrix time ~1190cyc of a ~2840cyc wave period (~50% duty).
//   Each SIMD hosts exactly 2 waves, one from EACH resident block; the two
//   blocks run identical barrier-locked loops, so their relative phase is
//   fixed at launch and persists. In-phase pairs leave the matrix pipe idle
//   half the time -> chip average ~46% = what we measure, invariant to all
//   intra-wave scheduling.
//   Fix under test: delay one block of each co-resident pair by ~half a
//   body period (s_sleep 22 ~ 1408cyc) before the main loop. Anti-phase is
//   the stable fast attractor (anti-phased blocks don't contend, in-phase
//   ones do). Pair parity ((l>>8)^l)&1 covers both plausible pairings
//   ((k,k+256) round-robin and (2k,2k+1) consecutive).
//   Everything else byte-identical to round-12 (32x32x16 D, counted-vmcnt Q
//   rotation, fenced C/D interleave, XCD decode, fused waitcnt+barrier).
// LDS = 8 (sF x2) + 16 (sXw x2) + 16 (sXp x2) = 40 KB; 2 blocks/CU.
// ---------------------------------------------------------------------------
__global__ __launch_bounds__(256, 2) void fused_main(
    const float* __restrict__ x, const unsigned short* __restrict__ f_bf,
    const unsigned short* __restrict__ Q1, const unsigned short* __restrict__ Q2,
    const float* __restrict__ pws, float* __restrict__ out) {
  // XCD-aware decode: l -> (p-tile, head, b-tile) with Q-sharers co-located.
  const int l = blockIdx.x;        // 0..511
  const int i = l >> 3;            // 0..63 within XCD
  const int g = (l & 7) * 4 + (i & 3);  // group = (p-tile, head), 0..31
  const int h = g >> 1;
  const int n0 = (g & 1) * 256;    // p tile
  const int m0 = (i >> 2) * 128;   // b tile
  const int t = threadIdx.x;
  const int wave = t >> 6, lane = t & 63;
  const int quad = lane >> 4, lr = lane & 15;
  const int el = lane & 31, half = lane >> 5;   // 32x32 fragment coords
  const int key8 = lr & 7;         // swizzle key for 128B-row buffer (sF)
  const int key2 = (lr >> 1) & 3;  // swizzle key for 64B-row buffers (sX*)

  __shared__ __align__(16) char sF[2 * 4096];
  __shared__ __align__(16) char sXw[2 * 8192];
  __shared__ __align__(16) char sXp[2 * 8192];

  // Xh B-operand fragments (16x16x32 B-step), loaded fp32, packed in-reg.
  bf16x8 xh[2][2];
#pragma unroll
  for (int bn = 0; bn < 2; ++bn)
#pragma unroll
    for (int s = 0; s < 2; ++s) {
      int b = m0 + wave * 32 + bn * 16 + lr;
      const float* xr = x + (size_t)b * 1024 + h * 64 + s * 32 + quad * 8;
      fl4 v0 = *(const fl4*)xr;
      fl4 v1 = *(const fl4*)(xr + 4);
      union { unsigned u[4]; bf16x8 v; } cv;
      cv.u[0] = pkbf(v0.x, v0.y);
      cv.u[1] = pkbf(v0.z, v0.w);
      cv.u[2] = pkbf(v1.x, v1.y);
      cv.u[3] = pkbf(v1.z, v1.w);
      xh[bn][s] = cv.v;
    }

  // ---- hoisted (loop-invariant) LDS byte offsets ----
  int af_off[2][2];  // B reads: sF row fm*16+lr, global chunk s*4+quad
#pragma unroll
  for (int fm = 0; fm < 2; ++fm)
#pragma unroll
    for (int s = 0; s < 2; ++s)
      af_off[fm][s] = (fm * 16 + lr) * 128 + (((s * 4 + quad) ^ key8) * 16);

  int cw_off[2][2];  // C writes: row wave*32+bn*16+lr, chunk fm*2+(quad>>1)
#pragma unroll
  for (int fm = 0; fm < 2; ++fm)
#pragma unroll
    for (int bn = 0; bn < 2; ++bn)
      cw_off[fm][bn] = (wave * 32 + bn * 16 + lr) * 64 +
                       (((fm * 2 + (quad >> 1)) ^ key2) * 16) + (quad & 1) * 8;

  // D A-frag reads (32x32x16): row = mt*32 + el, logical 16B chunk =
  // ks*2 + half, physical = logical ^ ((el&15)>>1 & 3) [matches cw swizzle;
  // (row>>1)&3 == ((row mod 16)>>1)&3 since row steps are multiples of 16].
  int axk[2];
  {
    int keyel = ((el & 15) >> 1) & 3;
#pragma unroll
    for (int ks = 0; ks < 2; ++ks)
      axk[ks] = el * 64 + (((ks * 2 + half) ^ keyel) * 16);
  }

  // sF staging source (swizzle applied on the GLOBAL side)
  const char* srcF;
  {
    int row = t >> 3, c = t & 7, cs = c ^ (row & 7);
    srcF = (const char*)f_bf + h * 128 + (size_t)row * 2048 + cs * 16;
  }

  // Q addressing: block-uniform base (SGPR) + per-lane 32-bit byte offset.
  // Lane layout (32x32 B-frag): p = wave*64 + nt*32 + el, f = ks*16+half*8+j.
  const char* qb1 = (const char*)Q1 + (size_t)(h * PP + n0) * FF * 2;
  const char* qb2 = (const char*)Q2 + (size_t)(h * PP + n0) * FF * 2;
  unsigned qo = (unsigned)(((wave * 64 + el) * FF + half * 8) * 2);

  f32x16 acc[4][2];
#pragma unroll
  for (int mt = 0; mt < 4; ++mt)
#pragma unroll
    for (int nt = 0; nt < 2; ++nt)
#pragma unroll
      for (int r = 0; r < 16; ++r) acc[mt][nt][r] = 0.f;

  f32x4 xf[2][2];
  bf16x8 q1v[2][2], q2v[2][2];  // [nt][ks], rotated across iterations
  bf16x8 awf[2][2], apf[2][2];  // [m-local][ks]

// B(k): Xf from sF buf SFB into xf (8 x 16x16x32 MFMA)
#define BSTEP(SFB) do {                                                      \
    _Pragma("unroll") for (int fm_ = 0; fm_ < 2; ++fm_)                      \
      _Pragma("unroll") for (int bn_ = 0; bn_ < 2; ++bn_)                    \
        xf[fm_][bn_] = (f32x4){0.f, 0.f, 0.f, 0.f};                          \
    _Pragma("unroll") for (int s_ = 0; s_ < 2; ++s_)                         \
      _Pragma("unroll") for (int fm_ = 0; fm_ < 2; ++fm_) {                  \
        bf16x8 af_ = *(const bf16x8*)(sF + (SFB) + af_off[fm_][s_]);         \
        _Pragma("unroll") for (int bn_ = 0; bn_ < 2; ++bn_)                  \
          xf[fm_][bn_] = __builtin_amdgcn_mfma_f32_16x16x32_bf16(            \
              af_, xh[bn_][s_], xf[fm_][bn_], 0, 0, 0);                      \
      }                                                                      \
  } while (0)

// C pack group (FM,BN) -> sXw/sXp at byte base XB (~20 VALU + 2 ds_write)
#define CPACK(FM, BN, XB) do {                                               \
    float v0_ = xf[FM][BN][0], v1_ = xf[FM][BN][1];                          \
    float v2_ = xf[FM][BN][2], v3_ = xf[FM][BN][3];                          \
    float p0_ = fmaxf(v0_, 0.f), p1_ = fmaxf(v1_, 0.f);                      \
    float p2_ = fmaxf(v2_, 0.f), p3_ = fmaxf(v3_, 0.f);                      \
    u32x2 w_, p_;                                                            \
    w_.x = pkbf(v0_ * p0_, v1_ * p1_);                                       \
    w_.y = pkbf(v2_ * p2_, v3_ * p3_);                                       \
    p_.x = pkbf(p0_, p1_);                                                   \
    p_.y = pkbf(p2_, p3_);                                                   \
    *(u32x2*)(sXw + (XB) + cw_off[FM][BN]) = w_;                             \
    *(u32x2*)(sXp + (XB) + cw_off[FM][BN]) = p_;                             \
  } while (0)

// D operand reads for mt-pair P from sX buf XA (8 ds_read_b128)
#define DREAD32(P, XA) do {                                                  \
    _Pragma("unroll") for (int m_ = 0; m_ < 2; ++m_)                         \
      _Pragma("unroll") for (int ks_ = 0; ks_ < 2; ++ks_) {                  \
        awf[m_][ks_] =                                                       \
            *(const bf16x8*)(sXw + (XA) + (P) * 4096 + m_ * 2048 + axk[ks_]);\
        apf[m_][ks_] =                                                       \
            *(const bf16x8*)(sXp + (XA) + (P) * 4096 + m_ * 2048 + axk[ks_]);\
      }                                                                      \
  } while (0)

// D MFMA quarter: mt-pair P, k-step KS (8 x 32x32x16 MFMA)
#define DM32(P, KS) do {                                                     \
    _Pragma("unroll") for (int m_ = 0; m_ < 2; ++m_)                         \
      _Pragma("unroll") for (int nt_ = 0; nt_ < 2; ++nt_) {                  \
        acc[(P) * 2 + m_][nt_] = __builtin_amdgcn_mfma_f32_32x32x16_bf16(    \
            awf[m_][KS], q1v[nt_][KS], acc[(P) * 2 + m_][nt_], 0, 0, 0);     \
        acc[(P) * 2 + m_][nt_] = __builtin_amdgcn_mfma_f32_32x32x16_bf16(    \
            apf[m_][KS], q2v[nt_][KS], acc[(P) * 2 + m_][nt_], 0, 0, 0);     \
      }                                                                      \
  } while (0)

// Q fragment loads (8 x 16B global, L2-hit); rotated: loaded one iter ahead
#define QLOAD() do {                                                         \
    _Pragma("unroll") for (int nt_ = 0; nt_ < 2; ++nt_)                      \
      _Pragma("unroll") for (int ks_ = 0; ks_ < 2; ++ks_) {                  \
        q1v[nt_][ks_] =                                                      \
            *(const bf16x8*)(qb1 + qo + nt_ * 262144 + ks_ * 32);            \
        q2v[nt_][ks_] =                                                      \
            *(const bf16x8*)(qb2 + qo + nt_ * 262144 + ks_ * 32);            \
      }                                                                      \
  } while (0)

// One pipeline body. PA: D reads sX[PA], stage writes sF[PA].
// PB = PA^1: B reads sF[PB], C writes sX[PB]. All compile-time.
#define BODY(PA_, PB_) do {                                                  \
    gload_lds16(srcF, sF + (PA_) * 4096 + t * 16);                           \
    srcF += 32 * 2048;                                                       \
    BSTEP((PB_) * 4096);                                                     \
    DREAD32(0, (PA_) * 8192);                                                \
    __builtin_amdgcn_sched_barrier(0);                                       \
    __builtin_amdgcn_s_setprio(1);                                           \
    CPACK(0, 0, (PB_) * 8192);                                               \
    DM32(0, 0);                                                              \
    __builtin_amdgcn_sched_barrier(0);                                       \
    CPACK(0, 1, (PB_) * 8192);                                               \
    DM32(0, 1);                                                              \
    DREAD32(1, (PA_) * 8192);                                                \
    __builtin_amdgcn_sched_barrier(0);                                       \
    CPACK(1, 0, (PB_) * 8192);                                               \
    DM32(1, 0);                                                              \
    __builtin_amdgcn_sched_barrier(0);                                       \
    CPACK(1, 1, (PB_) * 8192);                                               \
    DM32(1, 1);                                                              \
    __builtin_amdgcn_s_setprio(0);                                           \
    QLOAD();                                                                 \
    qo += 64;                                                                \
    /* counted wait: keep the 8 fresh Q loads in flight across the       */  \
    /* barrier; drain only older vmem (the sF DMA). lgkmcnt(0) publishes */  \
    /* C ds_writes and closes D ds_reads. Single asm: no scheduler gap.  */  \
    asm volatile("s_waitcnt vmcnt(8) lgkmcnt(0)\n\ts_barrier" ::: "memory"); \
    __builtin_amdgcn_sched_barrier(0);                                       \
  } while (0)

  // ---- prologue ----
  gload_lds16(srcF, sF + t * 16);          // tile0 -> sF buf0
  srcF += 32 * 2048;
  asm volatile("s_waitcnt vmcnt(0)\n\ts_barrier" ::: "memory");
  __builtin_amdgcn_sched_barrier(0);
  gload_lds16(srcF, sF + 4096 + t * 16);   // tile1 -> sF buf1
  srcF += 32 * 2048;
  BSTEP(0);                                 // B(0)+C(0) -> sXw/sXp buf0
  CPACK(0, 0, 0);
  CPACK(0, 1, 0);
  CPACK(1, 0, 0);
  CPACK(1, 1, 0);
  QLOAD();                                  // Q(0)
  qo += 64;
  asm volatile("s_waitcnt vmcnt(8) lgkmcnt(0)\n\ts_barrier" ::: "memory");
  __builtin_amdgcn_sched_barrier(0);

  // Anti-phase stagger: delay one block of each co-resident pair by ~half a
  // body period (~1408 cyc) so the pair's MFMA/VALU phases interleave on
  // the shared SIMDs instead of colliding. Parity (bit0 ^ bit8) covers both
  // plausible co-residency pairings. Uniform per block -> barrier-safe.
  if (((l >> 8) ^ l) & 1) {
    asm volatile("s_sleep 22" ::: "memory");
  }

  for (int it2 = 0; it2 < FF / 64; ++it2) {
    BODY(0, 1);
    BODY(1, 0);
  }

  // epilogue: subtract pws, store fp32 (32x32 C/D layout)
#pragma unroll
  for (int nt = 0; nt < 2; ++nt) {
    int p = n0 + wave * 64 + nt * 32 + el;
    float sub = pws[h * PP + p];
#pragma unroll
    for (int mt = 0; mt < 4; ++mt) {
#pragma unroll
      for (int gi = 0; gi < 4; ++gi) {
#pragma unroll
        for (int r = 0; r < 4; ++r) {
          int b = m0 + mt * 32 + gi * 8 + half * 4 + r;
          out[(size_t)b * (NH * PP) + h * PP + p] = acc[mt][nt][gi * 4 + r] - sub;
        }
      }
    }
  }
}

extern "C" void kernel_launch(void* const* d_in, const int* in_sizes, int n_in,
                              void* d_out, int out_size, void* d_ws, size_t ws_size,
                              hipStream_t stream) {
  const float* x = (const float*)d_in[0];
  const float* features = (const float*)d_in[1];
  const float* prototypes = (const float*)d_in[2];
  const float* theta = (const float*)d_in[3];
  const float* alpha = (const float*)d_in[4];
  const float* beta = (const float*)d_in[5];
  float* out = (float*)d_out;

  char* ws = (char*)d_ws;
  size_t off = 0;
  auto carve = [&](size_t bytes) -> char* {
    char* p = ws + off;
    off += (bytes + 255) & ~(size_t)255;
    return p;
  };
  // f_bf padded by 64 rows: fused_main's pipelined loop prefetches up to two
  // tiles past the end (data unused; keeps the main loop branch-free).
  unsigned short* f_bf = (unsigned short*)carve((size_t)(FF + 64) * 1024 * 2);
  unsigned short* p_bf = (unsigned short*)carve((size_t)PP * 1024 * 2);
  unsigned short* Q1 = (unsigned short*)carve((size_t)NH * PP * FF * 2);
  unsigned short* Q2 = (unsigned short*)carve((size_t)NH * PP * FF * 2);
  float* pws = (float*)carve((size_t)NH * PP * 4);

  const int ncvt = (FF + PP) * 1024 / 4;
  cvt_fp<<<(ncvt + 255) / 256, 256, 0, stream>>>(features, prototypes, f_bf, p_bf);
  hipMemsetAsync(pws, 0, (size_t)NH * PP * 4, stream);

  // Phase 1: prototypes -> Q1, Q2, pws
  gemm_proto<<<dim3(FF / 128, PP / 128, NH), 256, 0, stream>>>(
      p_bf, f_bf, Q1, Q2, pws, theta, alpha, beta);

  // Fused main GEMM (1-D grid, XCD-aware decode in-kernel)
  fused_main<<<dim3(512, 1, 1), 256, 0, stream>>>(
      x, f_bf, Q1, Q2, pws, out);
}